// Round 1
// baseline (25529.903 us; speedup 1.0000x reference)
//
#include <hip/hip_runtime.h>
#include <stdint.h>

// Problem constants
#define Bv 16
#define Sv 2048
#define Iv 128
#define Hv 512
#define Ov 128

typedef __bf16 v8bf __attribute__((ext_vector_type(8)));
typedef float v4f __attribute__((ext_vector_type(4)));
#define MFMA(a, b, c) __builtin_amdgcn_mfma_f32_16x16x32_bf16((a), (b), (c), 0, 0, 0)

__device__ __forceinline__ float sigf(float x) { return 1.0f / (1.0f + __expf(-x)); }
__device__ __forceinline__ float tanh_fast(float x) { return 2.0f / (1.0f + __expf(-2.0f * x)) - 1.0f; }

__device__ __forceinline__ unsigned f2bf(float f) {
  union { __bf16 h; unsigned short u; } c; c.h = (__bf16)f; return (unsigned)c.u;
}
__device__ __forceinline__ float bf2f(unsigned short u) {
  union { __bf16 h; unsigned short u; } c; c.u = u; return (float)c.h;
}

__device__ __forceinline__ v8bf cvt8(const float* p) {
  v8bf r;
#pragma unroll
  for (int i = 0; i < 8; i++) r[i] = (__bf16)p[i];
  return r;
}

// relaxed agent-scope atomics (sc0 sc1: bypass L1 + non-coherent per-XCD L2).
// Coherence point = Infinity Cache.
__device__ __forceinline__ uint64_t ld64(const uint64_t* p) {
  return __hip_atomic_load((uint64_t*)p, __ATOMIC_RELAXED, __HIP_MEMORY_SCOPE_AGENT);
}
__device__ __forceinline__ void st32(unsigned* p, unsigned v) {
  __hip_atomic_store(p, v, __ATOMIC_RELAXED, __HIP_MEMORY_SCOPE_AGENT);
}
__device__ __forceinline__ unsigned ld32(const unsigned* p) {
  return __hip_atomic_load((unsigned*)p, __ATOMIC_RELAXED, __HIP_MEMORY_SCOPE_AGENT);
}

// Payload word for hidden value (b, c): u32 = bf16(value) | tag<<16, tag = step id.
// Fragment-order layout: each (wave, lane) consumer's 32 words are 128B-contiguous.
// bits: [12:11]=wave (c>>7), [10:9]=lq ((c>>3)&3), [8:5]=b, [4:3]=kb ((c>>5)&3), [2:0]=e (c&7)
__device__ __forceinline__ int pidx(int b, int c) {
  return ((c >> 7) << 11) | (((c >> 3) & 3) << 9) | (b << 5) | (((c >> 5) & 3) << 3) | (c & 7);
}

// Poll this lane's 16-u64 fragment region until every word carries `tag`.
// 4-word probe first (one word per producer block feeding this lane) to keep
// steady poll BW low; full load + verify once probes match. Valve: wrong beats hang.
__device__ __forceinline__ void pollfrag(const unsigned* slot, int wl, unsigned tag, uint64_t* W) {
  const uint64_t* p = (const uint64_t*)slot + wl;
  const uint64_t want = ((uint64_t)tag << 16) | ((uint64_t)tag << 48);
  const uint64_t MSK = 0xffff0000ffff0000ull;
  unsigned r = 0;
  for (;;) {
    uint64_t a0 = ld64(p), a1 = ld64(p + 4), a2 = ld64(p + 8), a3 = ld64(p + 12);
    bool probe = ((a0 & MSK) == want) && ((a1 & MSK) == want) &&
                 ((a2 & MSK) == want) && ((a3 & MSK) == want);
    if (__all(probe)) {
#pragma unroll
      for (int i = 0; i < 16; i++) W[i] = ld64(p + i);
      bool ok = true;
#pragma unroll
      for (int i = 0; i < 16; i++) ok &= ((W[i] & MSK) == want);
      if (__all(ok)) return;
    }
    if (++r > (1u << 20)) {
#pragma unroll
      for (int i = 0; i < 16; i++) W[i] = ld64(p + i);
      return;
    }
  }
}

// Dual poll (two slots, latencies overlapped).
__device__ __forceinline__ void pollfrag2(const unsigned* sA, unsigned tA,
                                          const unsigned* sB, unsigned tB,
                                          int wl, uint64_t* WA, uint64_t* WB) {
  const uint64_t* pA = (const uint64_t*)sA + wl;
  const uint64_t* pB = (const uint64_t*)sB + wl;
  const uint64_t wantA = ((uint64_t)tA << 16) | ((uint64_t)tA << 48);
  const uint64_t wantB = ((uint64_t)tB << 16) | ((uint64_t)tB << 48);
  const uint64_t MSK = 0xffff0000ffff0000ull;
  unsigned r = 0;
  for (;;) {
    uint64_t a0 = ld64(pA), a1 = ld64(pA + 4), a2 = ld64(pA + 8), a3 = ld64(pA + 12);
    uint64_t b0 = ld64(pB), b1 = ld64(pB + 4), b2 = ld64(pB + 8), b3 = ld64(pB + 12);
    bool probe = ((a0 & MSK) == wantA) && ((a1 & MSK) == wantA) &&
                 ((a2 & MSK) == wantA) && ((a3 & MSK) == wantA) &&
                 ((b0 & MSK) == wantB) && ((b1 & MSK) == wantB) &&
                 ((b2 & MSK) == wantB) && ((b3 & MSK) == wantB);
    if (__all(probe)) {
#pragma unroll
      for (int i = 0; i < 16; i++) WA[i] = ld64(pA + i);
#pragma unroll
      for (int i = 0; i < 16; i++) WB[i] = ld64(pB + i);
      bool ok = true;
#pragma unroll
      for (int i = 0; i < 16; i++) ok &= ((WA[i] & MSK) == wantA) & ((WB[i] & MSK) == wantB);
      if (__all(ok)) return;
    }
    if (++r > (1u << 20)) {
#pragma unroll
      for (int i = 0; i < 16; i++) { WA[i] = ld64(pA + i); WB[i] = ld64(pB + i); }
      return;
    }
  }
}

// Strip tags, build 4 MFMA A-fragments (v8bf) from the 16 polled u64s.
__device__ __forceinline__ void mkfrags(const uint64_t* W, v8bf* ah) {
#pragma unroll
  for (int kb = 0; kb < 4; kb++) {
    union { v8bf v; uint32_t q[4]; } cc;
#pragma unroll
    for (int j = 0; j < 4; j++) {
      uint64_t w = W[kb * 4 + j];
      cc.q[j] = (uint32_t)(w & 0xffffu) | (((uint32_t)(w >> 32)) << 16);
    }
    ah[kb] = cc.v;
  }
}

__global__ __launch_bounds__(256, 1) void gru_fused(
    const float* __restrict__ x, const float* __restrict__ hs,
    const float* __restrict__ Wxz0, const float* __restrict__ Whz0, const float* __restrict__ bhz0,
    const float* __restrict__ Wxr0, const float* __restrict__ Whr0, const float* __restrict__ bhr0,
    const float* __restrict__ Wxz1, const float* __restrict__ Whz1, const float* __restrict__ bhz1,
    const float* __restrict__ Wxr1, const float* __restrict__ Whr1, const float* __restrict__ bhr1,
    const float* __restrict__ Why, const float* __restrict__ by,
    float* __restrict__ out, char* __restrict__ ws, int D) {
  const int tid = threadIdx.x;
  const int wave = tid >> 6;
  const int lane = tid & 63;
  const int lm = lane & 15;
  const int lq = lane >> 4;
  const int rb = tid >> 4;                 // batch row for elementwise/payload store
  const int rj = tid & 15;                 // col within block's 16-col slice
  const int wl = wave * 1024 + lane * 16;  // u64 offset of this lane's frag region
  const int m0 = D - 1;

  unsigned* prog = (unsigned*)ws;           // [32], zeroed by memset
  unsigned* h0d = (unsigned*)(ws + 16384);  // D slots x 8192 u32 (32KB/slot)
  unsigned* h1d = h0d + (size_t)D * 8192;   // 4 slots
  unsigned* u0d = h1d + 4 * 8192;           // 2 slots
  unsigned* u1d = u0d + 2 * 8192;           // 2 slots

  __shared__ float red[5][4][16][17];  // planes: 0=z 1=xr 2=hr 3=out 4=g

  const bool L0 = (blockIdx.x < 32);
  const int wg = L0 ? blockIdx.x : (blockIdx.x - 32);
  const int j0 = wg << 4;
  const bool OW = (!L0) && (wg < 8);
  const int jrow = j0 + lm;

  if (L0) {
    const int xk = wave * 32 + lq * 8;
    v8bf wzx0 = cvt8(Wxz0 + (size_t)jrow * Iv + xk);
    v8bf wrx0 = cvt8(Wxr0 + (size_t)jrow * Iv + xk);
    v8bf wzh[4], wrh[4];
#pragma unroll
    for (int kb = 0; kb < 4; kb++) {
      int k = wave * 128 + kb * 32 + lq * 8;
      wzh[kb] = cvt8(Whz0 + (size_t)jrow * Hv + k);
      wrh[kb] = cvt8(Whr0 + (size_t)jrow * Hv + k);
    }
    float bz = bhz0[j0 + rj], br = bhr0[j0 + rj];

    float hval = bf2f((unsigned short)f2bf(hs[((size_t)rb * 2 + 0) * Hv + j0 + rj]));
    st32(h0d + pidx(rb, j0 + rj), f2bf(hval) | (1u << 16));

    float4 xp0 = *(const float4*)(x + ((size_t)lm * Sv + 0) * Iv + xk);
    float4 xp1 = *(const float4*)(x + ((size_t)lm * Sv + 0) * Iv + xk + 4);

    for (int t = 0; t < Sv; ++t) {
      uint64_t W[16];
      pollfrag(h0d + (size_t)(t & m0) * 8192, wl, (unsigned)(t + 1), W);
      v8bf ah[4]; mkfrags(W, ah);
      v8bf ax;
      {
        float xf[8] = {xp0.x, xp0.y, xp0.z, xp0.w, xp1.x, xp1.y, xp1.z, xp1.w};
#pragma unroll
        for (int i = 0; i < 8; i++) ax[i] = (__bf16)xf[i];
      }
      v4f az = {0, 0, 0, 0}, axr = {0, 0, 0, 0}, ahr = {0, 0, 0, 0};
      az = MFMA(ax, wzx0, az);
      axr = MFMA(ax, wrx0, axr);
#pragma unroll
      for (int kb = 0; kb < 4; kb++) {
        az = MFMA(ah[kb], wzh[kb], az);
        ahr = MFMA(ah[kb], wrh[kb], ahr);
      }
#pragma unroll
      for (int v = 0; v < 4; v++) {
        red[0][wave][lq * 4 + v][lm] = az[v];
        red[1][wave][lq * 4 + v][lm] = axr[v];
        red[2][wave][lq * 4 + v][lm] = ahr[v];
      }
      if (t + 1 < Sv) {  // prefetch next x (overlaps barrier)
        xp0 = *(const float4*)(x + ((size_t)lm * Sv + (t + 1)) * Iv + xk);
        xp1 = *(const float4*)(x + ((size_t)lm * Sv + (t + 1)) * Iv + xk + 4);
      }
      if (t >= D - 1) {  // backpressure vs L1's y0 consumption (overlaps barrier)
        unsigned need = (unsigned)(t - D + 2), it = 0;
        while (ld32(prog + (tid & 31)) < need)
          if (++it > (1u << 20)) break;
      }
      __syncthreads();
      float zs = 0, xrs = 0, hrs = 0;
#pragma unroll
      for (int w = 0; w < 4; w++) {
        zs += red[0][w][rb][rj];
        xrs += red[1][w][rb][rj];
        hrs += red[2][w][rb][rj];
      }
      float z = sigf(zs + bz);
      float r = sigf(xrs + hrs + br);
      st32(u0d + (size_t)(t & 1) * 8192 + pidx(rb, j0 + rj),
           f2bf(r * hval) | ((unsigned)(t + 1) << 16));
      uint64_t WU[16];
      pollfrag(u0d + (size_t)(t & 1) * 8192, wl, (unsigned)(t + 1), WU);
      v8bf au[4]; mkfrags(WU, au);
      v4f ag = {0, 0, 0, 0};
#pragma unroll
      for (int kb = 0; kb < 4; kb++) ag = MFMA(au[kb], wrh[kb], ag);
#pragma unroll
      for (int v = 0; v < 4; v++) red[4][wave][lq * 4 + v][lm] = ag[v];
      __syncthreads();
      float gs = 0;
#pragma unroll
      for (int w = 0; w < 4; w++) gs += red[4][w][rb][rj];
      float g = tanh_fast(xrs + gs + br);  // faithful to source bug
      float hn = z * hval + (1.f - z) * g;
      unsigned hb = f2bf(hn);
      hval = bf2f((unsigned short)hb);
      st32(h0d + (size_t)((t + 1) & m0) * 8192 + pidx(rb, j0 + rj),
           hb | ((unsigned)(t + 2) << 16));
      if (t == Sv - 1)
        out[(size_t)Bv * Sv * Ov + ((size_t)rb * 2 + 0) * Hv + j0 + rj] = hn;
    }
  } else {
    v8bf wzx1[4], wrx1[4], wzh[4], wrh[4], wo[4];
#pragma unroll
    for (int kb = 0; kb < 4; kb++) {
      int k = wave * 128 + kb * 32 + lq * 8;
      wzx1[kb] = cvt8(Wxz1 + (size_t)jrow * Hv + k);
      wrx1[kb] = cvt8(Wxr1 + (size_t)jrow * Hv + k);
      wzh[kb] = cvt8(Whz1 + (size_t)jrow * Hv + k);
      wrh[kb] = cvt8(Whr1 + (size_t)jrow * Hv + k);
      if (OW) wo[kb] = cvt8(Why + (size_t)jrow * Hv + k);
    }
    float bz = bhz1[j0 + rj], br = bhr1[j0 + rj];
    float bo = OW ? by[j0 + rj] : 0.f;

    float hval = bf2f((unsigned short)f2bf(hs[((size_t)rb * 2 + 1) * Hv + j0 + rj]));
    st32(h1d + pidx(rb, j0 + rj), f2bf(hval) | (1u << 16));

    for (int t = 0; t < Sv; ++t) {
      // y0_t = h0 tag t+2 at slot (t+1)&m0; h1_{t-1} = tag t+1 at slot t&3
      uint64_t WY[16], WH[16];
      pollfrag2(h0d + (size_t)((t + 1) & m0) * 8192, (unsigned)(t + 2),
                h1d + (size_t)(t & 3) * 8192, (unsigned)(t + 1), wl, WY, WH);
      v8bf ay[4], ahf[4];
      mkfrags(WY, ay);
      mkfrags(WH, ahf);
      v4f az = {0, 0, 0, 0}, axr = {0, 0, 0, 0}, ahr = {0, 0, 0, 0}, ao = {0, 0, 0, 0};
#pragma unroll
      for (int kb = 0; kb < 4; kb++) {
        az = MFMA(ay[kb], wzx1[kb], az);
        az = MFMA(ahf[kb], wzh[kb], az);
        axr = MFMA(ay[kb], wrx1[kb], axr);
        ahr = MFMA(ahf[kb], wrh[kb], ahr);
      }
      if (OW && t > 0) {
#pragma unroll
        for (int kb = 0; kb < 4; kb++) ao = MFMA(ahf[kb], wo[kb], ao);  // out_{t-1}
      }
#pragma unroll
      for (int v = 0; v < 4; v++) {
        red[0][wave][lq * 4 + v][lm] = az[v];
        red[1][wave][lq * 4 + v][lm] = axr[v];
        red[2][wave][lq * 4 + v][lm] = ahr[v];
        if (OW) red[3][wave][lq * 4 + v][lm] = ao[v];
      }
      __syncthreads();
      if (tid == 0) st32(prog + wg, (unsigned)(t + 1));  // y0_t consumed (all waves polled)
      float zs = 0, xrs = 0, hrs = 0, os = 0;
#pragma unroll
      for (int w = 0; w < 4; w++) {
        zs += red[0][w][rb][rj];
        xrs += red[1][w][rb][rj];
        hrs += red[2][w][rb][rj];
        if (OW) os += red[3][w][rb][rj];
      }
      float z = sigf(zs + bz);
      float r = sigf(xrs + hrs + br);
      st32(u1d + (size_t)(t & 1) * 8192 + pidx(rb, j0 + rj),
           f2bf(r * hval) | ((unsigned)(t + 1) << 16));
      if (OW && t > 0) out[((size_t)rb * Sv + (t - 1)) * Ov + j0 + rj] = os + bo;
      uint64_t WU[16];
      pollfrag(u1d + (size_t)(t & 1) * 8192, wl, (unsigned)(t + 1), WU);
      v8bf au[4]; mkfrags(WU, au);
      v4f ag = {0, 0, 0, 0};
#pragma unroll
      for (int kb = 0; kb < 4; kb++) ag = MFMA(au[kb], wrh[kb], ag);
#pragma unroll
      for (int v = 0; v < 4; v++) red[4][wave][lq * 4 + v][lm] = ag[v];
      __syncthreads();
      float gs = 0;
#pragma unroll
      for (int w = 0; w < 4; w++) gs += red[4][w][rb][rj];
      float g = tanh_fast(xrs + gs + br);
      float hn = z * hval + (1.f - z) * g;
      unsigned hb = f2bf(hn);
      hval = bf2f((unsigned short)hb);
      st32(h1d + (size_t)((t + 1) & 3) * 8192 + pidx(rb, j0 + rj),
           hb | ((unsigned)(t + 2) << 16));
      if (t == Sv - 1)
        out[(size_t)Bv * Sv * Ov + ((size_t)rb * 2 + 1) * Hv + j0 + rj] = hn;
    }
    if (OW) {  // tail: out_{S-1} from y1_{S-1} = h1 tag S+1 at slot S&3
      uint64_t W[16];
      pollfrag(h1d + (size_t)(Sv & 3) * 8192, wl, (unsigned)(Sv + 1), W);
      v8bf ah[4]; mkfrags(W, ah);
      v4f ao = {0, 0, 0, 0};
#pragma unroll
      for (int kb = 0; kb < 4; kb++) ao = MFMA(ah[kb], wo[kb], ao);
#pragma unroll
      for (int v = 0; v < 4; v++) red[3][wave][lq * 4 + v][lm] = ao[v];
      __syncthreads();
      float os = 0;
#pragma unroll
      for (int w = 0; w < 4; w++) os += red[3][w][rb][rj];
      out[((size_t)rb * Sv + (Sv - 1)) * Ov + j0 + rj] = os + bo;
    }
  }
}

extern "C" void kernel_launch(void* const* d_in, const int* in_sizes, int n_in,
                              void* d_out, int out_size, void* d_ws, size_t ws_size,
                              hipStream_t stream) {
  const float* x = (const float*)d_in[0];
  const float* hs = (const float*)d_in[1];
  const float* Wxz0 = (const float*)d_in[2];
  const float* Whz0 = (const float*)d_in[3];
  const float* bhz0 = (const float*)d_in[4];
  const float* Wxr0 = (const float*)d_in[5];
  const float* Whr0 = (const float*)d_in[6];
  const float* bhr0 = (const float*)d_in[7];
  const float* Wxz1 = (const float*)d_in[8];
  const float* Whz1 = (const float*)d_in[9];
  const float* bhz1 = (const float*)d_in[10];
  const float* Wxr1 = (const float*)d_in[11];
  const float* Whr1 = (const float*)d_in[12];
  const float* bhr1 = (const float*)d_in[13];
  const float* Why = (const float*)d_in[14];
  const float* by = (const float*)d_in[15];
  float* out = (float*)d_out;

  // y0-ring depth: largest pow2 (<=64, >=4) fitting ws (32KB tagged slots)
  int D = 64;
  while (D > 4 && 16384 + (size_t)(D + 8) * 32768 > ws_size) D >>= 1;

  // zero prog + all payload rings (tags must start != any valid step tag)
  size_t msz = 16384 + (size_t)(D + 8) * 32768;
  if (msz > ws_size) msz = ws_size;
  hipMemsetAsync(d_ws, 0, msz, stream);
  hipLaunchKernelGGL(gru_fused, dim3(64), dim3(256), 0, stream,
                     x, hs, Wxz0, Whz0, bhz0, Wxr0, Whr0, bhr0,
                     Wxz1, Whz1, bhz1, Wxr1, Whr1, bhr1, Why, by,
                     out, (char*)d_ws, D);
}

// Round 2
// 24832.045 us; speedup vs baseline: 1.0281x; 1.0281x over previous
//
#include <hip/hip_runtime.h>
#include <stdint.h>

// Problem constants
#define Bv 16
#define Sv 2048
#define Iv 128
#define Hv 512
#define Ov 128

typedef __bf16 v8bf __attribute__((ext_vector_type(8)));
typedef float v4f __attribute__((ext_vector_type(4)));
#define MFMA(a, b, c) __builtin_amdgcn_mfma_f32_16x16x32_bf16((a), (b), (c), 0, 0, 0)

__device__ __forceinline__ float sigf(float x) { return 1.0f / (1.0f + __expf(-x)); }
__device__ __forceinline__ float tanh_fast(float x) { return 2.0f / (1.0f + __expf(-2.0f * x)) - 1.0f; }

__device__ __forceinline__ unsigned f2bf(float f) {
  union { __bf16 h; unsigned short u; } c; c.h = (__bf16)f; return (unsigned)c.u;
}
__device__ __forceinline__ float bf2f(unsigned short u) {
  union { __bf16 h; unsigned short u; } c; c.u = u; return (float)c.h;
}

__device__ __forceinline__ v8bf cvt8(const float* p) {
  v8bf r;
#pragma unroll
  for (int i = 0; i < 8; i++) r[i] = (__bf16)p[i];
  return r;
}

// relaxed agent-scope atomics (bypass L1 + non-coherent per-XCD L2).
// Coherence point = Infinity Cache.
__device__ __forceinline__ uint64_t ld64(const uint64_t* p) {
  return __hip_atomic_load((uint64_t*)p, __ATOMIC_RELAXED, __HIP_MEMORY_SCOPE_AGENT);
}
__device__ __forceinline__ void st32(unsigned* p, unsigned v) {
  __hip_atomic_store(p, v, __ATOMIC_RELAXED, __HIP_MEMORY_SCOPE_AGENT);
}
__device__ __forceinline__ unsigned ld32(const unsigned* p) {
  return __hip_atomic_load((unsigned*)p, __ATOMIC_RELAXED, __HIP_MEMORY_SCOPE_AGENT);
}

// Producer-side: pack this thread's bf16 with its rj-neighbor's, even threads
// store one u32. Slot data layout: u32[b*256 + col/2].
__device__ __forceinline__ void store_slice(unsigned* dslot, int rb, int j0, int rj, float val) {
  unsigned bits = f2bf(val);
  unsigned nb = (unsigned)__shfl_xor((int)bits, 1);
  if ((rj & 1) == 0)
    st32(dslot + rb * 256 + ((j0 + rj) >> 1), bits | (nb << 16));
}

// Per-wave sentinel post: drain THIS WAVE's payload stores (vmcnt), then lane0
// posts one word. No block barrier needed. Payload visible before sentinel.
__device__ __forceinline__ void wave_post(unsigned* s, int idx, unsigned tag, int lane) {
  asm volatile("s_waitcnt vmcnt(0)" ::: "memory");
  if (lane == 0) st32(s + idx, tag);
}

// Poll 128 per-(block,wave) sentinel words (512B) until all == want.
// One round = 2 dword loads per lane. Valve: wrong beats hang.
__device__ __forceinline__ void pollw(const unsigned* s, unsigned want, int lane) {
  unsigned r = 0;
  for (;;) {
    unsigned a = ld32(s + lane);
    unsigned b = ld32(s + 64 + lane);
    if (__all((a == want) && (b == want)) || ++r > (1u << 20)) break;
  }
  asm volatile("" ::: "memory");
}
__device__ __forceinline__ void pollw2(const unsigned* sA, unsigned wA,
                                       const unsigned* sB, unsigned wB, int lane) {
  unsigned r = 0;
  for (;;) {
    unsigned a0 = ld32(sA + lane), a1 = ld32(sA + 64 + lane);
    unsigned b0 = ld32(sB + lane), b1 = ld32(sB + 64 + lane);
    if (__all((a0 == wA) && (a1 == wA) && (b0 == wB) && (b1 == wB)) || ++r > (1u << 20)) break;
  }
  asm volatile("" ::: "memory");
}

// One-shot fragment-direct read: 4 MFMA A-fragments (row b=lm, k=k0+kb*32)
// straight from the payload slot. Safe: payload committed before sentinel,
// and these loads issue only after the sentinel was observed.
__device__ __forceinline__ void ldfrags(const unsigned* slot, int lm, int k0, v8bf* a) {
  const uint64_t* p = (const uint64_t*)slot + (size_t)lm * 128;
#pragma unroll
  for (int kb = 0; kb < 4; kb++) {
    int ci = (k0 + kb * 32) >> 2;  // u64 index within row
    uint64_t w0 = ld64(p + ci);
    uint64_t w1 = ld64(p + ci + 1);
    union { v8bf v; uint64_t q[2]; } u;
    u.q[0] = w0; u.q[1] = w1;
    a[kb] = u.v;
  }
}
__device__ __forceinline__ float ldhval(const unsigned* slot, int rb, int j) {
  unsigned hw = ld32(slot + rb * 256 + (j >> 1));
  return bf2f((unsigned short)((j & 1) ? (hw >> 16) : (hw & 0xffffu)));
}

__global__ __launch_bounds__(256, 1) void gru_fused(
    const float* __restrict__ x, const float* __restrict__ hs,
    const float* __restrict__ Wxz0, const float* __restrict__ Whz0, const float* __restrict__ bhz0,
    const float* __restrict__ Wxr0, const float* __restrict__ Whr0, const float* __restrict__ bhr0,
    const float* __restrict__ Wxz1, const float* __restrict__ Whz1, const float* __restrict__ bhz1,
    const float* __restrict__ Wxr1, const float* __restrict__ Whr1, const float* __restrict__ bhr1,
    const float* __restrict__ Why, const float* __restrict__ by,
    float* __restrict__ out, char* __restrict__ ws, int D) {
  const int tid = threadIdx.x;
  const int wave = tid >> 6;
  const int lane = tid & 63;
  const int lm = lane & 15;
  const int lq = lane >> 4;
  const int rb = tid >> 4;       // batch row for elementwise/payload store
  const int rj = tid & 15;       // col within block's 16-col slice
  const int k0 = wave * 128 + lq * 8;  // H-dim fragment k-offset
  const int m0 = D - 1;

  unsigned* prog = (unsigned*)ws;            // [32], zeroed by memset
  unsigned* h0s = (unsigned*)(ws + 1024);    // [D][128] per-wave sentinels
  unsigned* h1s = h0s + D * 128;             // [4][128]
  unsigned* u0s = h1s + 4 * 128;             // [2][128]
  unsigned* u1s = u0s + 2 * 128;             // [2][128]
  unsigned* h0d = (unsigned*)(ws + 16384);   // [D][4096] payload (16KB/slot)
  unsigned* h1d = h0d + (size_t)D * 4096;    // [4][4096]
  unsigned* u0d = h1d + 4 * 4096;            // [2][4096]
  unsigned* u1d = u0d + 2 * 4096;            // [2][4096]

  __shared__ float red[5][4][16][17];  // planes: 0=z 1=xr 2=hr 3=out 4=g

  const bool L0 = (blockIdx.x < 32);
  const int wg = L0 ? blockIdx.x : (blockIdx.x - 32);
  const int j0 = wg << 4;
  const bool OW = (!L0) && (wg < 8);
  const int jrow = j0 + lm;
  const int sidx = wg * 4 + wave;

  // ---- initial hidden state -> payload slot 0, per-wave sentinel tag 1 ----
  {
    float h0v = hs[((size_t)rb * 2 + (L0 ? 0 : 1)) * Hv + j0 + rj];
    store_slice(L0 ? h0d : h1d, rb, j0, rj, h0v);
    wave_post(L0 ? h0s : h1s, sidx, 1u, lane);
  }

  if (L0) {
    const int xk = wave * 32 + lq * 8;
    v8bf wzx0 = cvt8(Wxz0 + (size_t)jrow * Iv + xk);
    v8bf wrx0 = cvt8(Wxr0 + (size_t)jrow * Iv + xk);
    v8bf wzh[4], wrh[4];
#pragma unroll
    for (int kb = 0; kb < 4; kb++) {
      int k = wave * 128 + kb * 32 + lq * 8;
      wzh[kb] = cvt8(Whz0 + (size_t)jrow * Hv + k);
      wrh[kb] = cvt8(Whr0 + (size_t)jrow * Hv + k);
    }
    float bz = bhz0[j0 + rj], br = bhr0[j0 + rj];

    float4 xp0 = *(const float4*)(x + ((size_t)lm * Sv + 0) * Iv + xk);
    float4 xp1 = *(const float4*)(x + ((size_t)lm * Sv + 0) * Iv + xk + 4);

    for (int t = 0; t < Sv; ++t) {
      pollw(h0s + (t & m0) * 128, (unsigned)(t + 1), lane);
      v8bf ah[4];
      ldfrags(h0d + (size_t)(t & m0) * 4096, lm, k0, ah);
      float hval = ldhval(h0d + (size_t)(t & m0) * 4096, rb, j0 + rj);
      v8bf ax;
      {
        float xf[8] = {xp0.x, xp0.y, xp0.z, xp0.w, xp1.x, xp1.y, xp1.z, xp1.w};
#pragma unroll
        for (int i = 0; i < 8; i++) ax[i] = (__bf16)xf[i];
      }
      v4f az = {0, 0, 0, 0}, axr = {0, 0, 0, 0}, ahr = {0, 0, 0, 0};
      az = MFMA(ax, wzx0, az);
      axr = MFMA(ax, wrx0, axr);
#pragma unroll
      for (int kb = 0; kb < 4; kb++) {
        az = MFMA(ah[kb], wzh[kb], az);
        ahr = MFMA(ah[kb], wrh[kb], ahr);
      }
#pragma unroll
      for (int v = 0; v < 4; v++) {
        red[0][wave][lq * 4 + v][lm] = az[v];
        red[1][wave][lq * 4 + v][lm] = axr[v];
        red[2][wave][lq * 4 + v][lm] = ahr[v];
      }
      __syncthreads();
      float zs = 0, xrs = 0, hrs = 0;
#pragma unroll
      for (int w = 0; w < 4; w++) {
        zs += red[0][w][rb][rj];
        xrs += red[1][w][rb][rj];
        hrs += red[2][w][rb][rj];
      }
      float z = sigf(zs + bz);
      float r = sigf(xrs + hrs + br);
      store_slice(u0d + (size_t)(t & 1) * 4096, rb, j0, rj, r * hval);
      wave_post(u0s + (t & 1) * 128, sidx, (unsigned)(t + 1), lane);
      if (t + 1 < Sv) {  // prefetch next x: overlaps the u-hop
        xp0 = *(const float4*)(x + ((size_t)lm * Sv + (t + 1)) * Iv + xk);
        xp1 = *(const float4*)(x + ((size_t)lm * Sv + (t + 1)) * Iv + xk + 4);
      }
      if (t >= D - 1) {  // backpressure vs L1's y0 consumption (overlaps u-hop)
        unsigned need = (unsigned)(t - D + 2), it = 0;
        while (ld32(prog + (tid & 31)) < need)
          if (++it > (1u << 20)) break;
      }
      pollw(u0s + (t & 1) * 128, (unsigned)(t + 1), lane);
      v8bf au[4];
      ldfrags(u0d + (size_t)(t & 1) * 4096, lm, k0, au);
      v4f ag = {0, 0, 0, 0};
#pragma unroll
      for (int kb = 0; kb < 4; kb++) ag = MFMA(au[kb], wrh[kb], ag);
#pragma unroll
      for (int v = 0; v < 4; v++) red[4][wave][lq * 4 + v][lm] = ag[v];
      __syncthreads();
      float gs = 0;
#pragma unroll
      for (int w = 0; w < 4; w++) gs += red[4][w][rb][rj];
      float g = tanh_fast(xrs + gs + br);  // faithful to source bug
      float hn = z * hval + (1.f - z) * g;
      store_slice(h0d + (size_t)((t + 1) & m0) * 4096, rb, j0, rj, hn);
      wave_post(h0s + ((t + 1) & m0) * 128, sidx, (unsigned)(t + 2), lane);
      if (t == Sv - 1)
        out[(size_t)Bv * Sv * Ov + ((size_t)rb * 2 + 0) * Hv + j0 + rj] = hn;
    }
  } else {
    v8bf wzx1[4], wrx1[4], wzh[4], wrh[4], wo[4];
#pragma unroll
    for (int kb = 0; kb < 4; kb++) {
      int k = wave * 128 + kb * 32 + lq * 8;
      wzx1[kb] = cvt8(Wxz1 + (size_t)jrow * Hv + k);
      wrx1[kb] = cvt8(Wxr1 + (size_t)jrow * Hv + k);
      wzh[kb] = cvt8(Whz1 + (size_t)jrow * Hv + k);
      wrh[kb] = cvt8(Whr1 + (size_t)jrow * Hv + k);
      if (OW) wo[kb] = cvt8(Why + (size_t)jrow * Hv + k);
    }
    float bz = bhz1[j0 + rj], br = bhr1[j0 + rj];
    float bo = OW ? by[j0 + rj] : 0.f;

    for (int t = 0; t < Sv; ++t) {
      // y0_t = h0 tag t+2 at slot (t+1)&m0; h1_t = tag t+1 at slot t&3
      pollw2(h0s + ((t + 1) & m0) * 128, (unsigned)(t + 2),
             h1s + (t & 3) * 128, (unsigned)(t + 1), lane);
      v8bf ay[4], ahf[4];
      ldfrags(h0d + (size_t)((t + 1) & m0) * 4096, lm, k0, ay);
      ldfrags(h1d + (size_t)(t & 3) * 4096, lm, k0, ahf);
      float hval = ldhval(h1d + (size_t)(t & 3) * 4096, rb, j0 + rj);
      v4f az = {0, 0, 0, 0}, axr = {0, 0, 0, 0}, ahr = {0, 0, 0, 0}, ao = {0, 0, 0, 0};
#pragma unroll
      for (int kb = 0; kb < 4; kb++) {
        az = MFMA(ay[kb], wzx1[kb], az);
        az = MFMA(ahf[kb], wzh[kb], az);
        axr = MFMA(ay[kb], wrx1[kb], axr);
        ahr = MFMA(ahf[kb], wrh[kb], ahr);
      }
      if (OW && t > 0) {
#pragma unroll
        for (int kb = 0; kb < 4; kb++) ao = MFMA(ahf[kb], wo[kb], ao);  // out_{t-1}
      }
#pragma unroll
      for (int v = 0; v < 4; v++) {
        red[0][wave][lq * 4 + v][lm] = az[v];
        red[1][wave][lq * 4 + v][lm] = axr[v];
        red[2][wave][lq * 4 + v][lm] = ahr[v];
        if (OW) red[3][wave][lq * 4 + v][lm] = ao[v];
      }
      __syncthreads();
      if (tid == 0) st32(prog + wg, (unsigned)(t + 1));  // y0_t consumed by all waves
      float zs = 0, xrs = 0, hrs = 0, os = 0;
#pragma unroll
      for (int w = 0; w < 4; w++) {
        zs += red[0][w][rb][rj];
        xrs += red[1][w][rb][rj];
        hrs += red[2][w][rb][rj];
        if (OW) os += red[3][w][rb][rj];
      }
      float z = sigf(zs + bz);
      float r = sigf(xrs + hrs + br);
      store_slice(u1d + (size_t)(t & 1) * 4096, rb, j0, rj, r * hval);
      wave_post(u1s + (t & 1) * 128, sidx, (unsigned)(t + 1), lane);
      if (OW && t > 0) out[((size_t)rb * Sv + (t - 1)) * Ov + j0 + rj] = os + bo;
      pollw(u1s + (t & 1) * 128, (unsigned)(t + 1), lane);
      v8bf au[4];
      ldfrags(u1d + (size_t)(t & 1) * 4096, lm, k0, au);
      v4f ag = {0, 0, 0, 0};
#pragma unroll
      for (int kb = 0; kb < 4; kb++) ag = MFMA(au[kb], wrh[kb], ag);
#pragma unroll
      for (int v = 0; v < 4; v++) red[4][wave][lq * 4 + v][lm] = ag[v];
      __syncthreads();
      float gs = 0;
#pragma unroll
      for (int w = 0; w < 4; w++) gs += red[4][w][rb][rj];
      float g = tanh_fast(xrs + gs + br);
      float hn = z * hval + (1.f - z) * g;
      store_slice(h1d + (size_t)((t + 1) & 3) * 4096, rb, j0, rj, hn);
      wave_post(h1s + ((t + 1) & 3) * 128, sidx, (unsigned)(t + 2), lane);
      if (t == Sv - 1)
        out[(size_t)Bv * Sv * Ov + ((size_t)rb * 2 + 1) * Hv + j0 + rj] = hn;
    }
    if (OW) {  // tail: out_{S-1} from y1_{S-1} = h1 tag S+1 at slot S&3
      pollw(h1s + (Sv & 3) * 128, (unsigned)(Sv + 1), lane);
      v8bf ah[4];
      ldfrags(h1d + (size_t)(Sv & 3) * 4096, lm, k0, ah);
      v4f ao = {0, 0, 0, 0};
#pragma unroll
      for (int kb = 0; kb < 4; kb++) ao = MFMA(ah[kb], wo[kb], ao);
#pragma unroll
      for (int v = 0; v < 4; v++) red[3][wave][lq * 4 + v][lm] = ao[v];
      __syncthreads();
      float os = 0;
#pragma unroll
      for (int w = 0; w < 4; w++) os += red[3][w][rb][rj];
      out[((size_t)rb * Sv + (Sv - 1)) * Ov + j0 + rj] = os + bo;
    }
  }
}

extern "C" void kernel_launch(void* const* d_in, const int* in_sizes, int n_in,
                              void* d_out, int out_size, void* d_ws, size_t ws_size,
                              hipStream_t stream) {
  const float* x = (const float*)d_in[0];
  const float* hs = (const float*)d_in[1];
  const float* Wxz0 = (const float*)d_in[2];
  const float* Whz0 = (const float*)d_in[3];
  const float* bhz0 = (const float*)d_in[4];
  const float* Wxr0 = (const float*)d_in[5];
  const float* Whr0 = (const float*)d_in[6];
  const float* bhr0 = (const float*)d_in[7];
  const float* Wxz1 = (const float*)d_in[8];
  const float* Whz1 = (const float*)d_in[9];
  const float* bhz1 = (const float*)d_in[10];
  const float* Wxr1 = (const float*)d_in[11];
  const float* Whr1 = (const float*)d_in[12];
  const float* bhr1 = (const float*)d_in[13];
  const float* Why = (const float*)d_in[14];
  const float* by = (const float*)d_in[15];
  float* out = (float*)d_out;

  // y0-ring depth: largest pow2 (<=16, >=4) fitting ws.
  // Cap 16 so per-wave sentinel arrays ([D][128] u32) stay inside the
  // 16KB memset region (D=16 -> sentinels end at 1024+13KB).
  int D = 16;
  while (D > 4 && 16384 + (size_t)(D + 8) * 16384 > ws_size) D >>= 1;

  hipMemsetAsync(d_ws, 0, 16384, stream);  // zero prog + all sentinels
  hipLaunchKernelGGL(gru_fused, dim3(64), dim3(256), 0, stream,
                     x, hs, Wxz0, Whz0, bhz0, Wxr0, Whr0, bhr0,
                     Wxz1, Whz1, bhz1, Wxr1, Whr1, bhr1, Why, by,
                     out, (char*)d_ws, D);
}

// Round 3
// 9329.284 us; speedup vs baseline: 2.7365x; 2.6617x over previous
//
#include <hip/hip_runtime.h>
#include <stdint.h>

// Problem constants
#define Bv 16
#define Sv 2048
#define Iv 128
#define Hv 512
#define Ov 128
#define RP 520  // staged LDS row pitch in ushorts

typedef __bf16 v8bf __attribute__((ext_vector_type(8)));
typedef float v4f __attribute__((ext_vector_type(4)));
#define MFMA(a, b, c) __builtin_amdgcn_mfma_f32_16x16x32_bf16((a), (b), (c), 0, 0, 0)

__device__ __forceinline__ float sigf(float x) { return 1.0f / (1.0f + __expf(-x)); }
__device__ __forceinline__ float tanh_fast(float x) { return 2.0f / (1.0f + __expf(-2.0f * x)) - 1.0f; }

__device__ __forceinline__ unsigned f2bf(float f) {
  union { __bf16 h; unsigned short u; } c; c.h = (__bf16)f; return (unsigned)c.u;
}
__device__ __forceinline__ float bf2f(unsigned short u) {
  union { __bf16 h; unsigned short u; } c; c.u = u; return (float)c.h;
}

__device__ __forceinline__ v8bf cvt8(const float* p) {
  v8bf r;
#pragma unroll
  for (int i = 0; i < 8; i++) r[i] = (__bf16)p[i];
  return r;
}

// LDS-only barrier: syncs waves + LDS ordering WITHOUT draining vmcnt.
// In-flight UC payload stores / global prefetch loads keep flying.
__device__ __forceinline__ void lgkm_barrier() {
  asm volatile("s_waitcnt lgkmcnt(0)\n\ts_barrier" ::: "memory");
}

// relaxed agent-scope atomics (bypass non-coherent per-XCD L2).
// Coherence point = Infinity Cache.
__device__ __forceinline__ uint64_t ld64(const uint64_t* p) {
  return __hip_atomic_load((uint64_t*)p, __ATOMIC_RELAXED, __HIP_MEMORY_SCOPE_AGENT);
}
__device__ __forceinline__ void st32(unsigned* p, unsigned v) {
  __hip_atomic_store(p, v, __ATOMIC_RELAXED, __HIP_MEMORY_SCOPE_AGENT);
}
__device__ __forceinline__ unsigned ld32(const unsigned* p) {
  return __hip_atomic_load((unsigned*)p, __ATOMIC_RELAXED, __HIP_MEMORY_SCOPE_AGENT);
}

// Producer-side: pack this thread's bf16 with its rj-neighbor's, even threads
// store one u32. Slot data layout: u32[rb*256 + col/2].
__device__ __forceinline__ void store_slice(unsigned* dslot, int rb, int j0, int rj, float val) {
  unsigned bits = f2bf(val);
  unsigned nb = (unsigned)__shfl_xor((int)bits, 1);
  if ((rj & 1) == 0)
    st32(dslot + rb * 256 + ((j0 + rj) >> 1), bits | (nb << 16));
}

// Poll 32 sentinel words (128 B) until all == want. Retry round = ONE 4B load.
__device__ __forceinline__ void poll1(const unsigned* s, unsigned want, int tid) {
  unsigned r = 0;
  for (;;) {
    unsigned v = ld32(s + (tid & 31));
    if (__all(v == want) || ++r > (1u << 20)) break;  // valve: wrong beats hang
  }
}
__device__ __forceinline__ void poll2(const unsigned* sA, unsigned wA,
                                      const unsigned* sB, unsigned wB, int tid) {
  unsigned r = 0;
  for (;;) {
    unsigned a = ld32(sA + (tid & 31));
    unsigned b = ld32(sB + (tid & 31));
    if (__all((a == wA) && (b == wB)) || ++r > (1u << 20)) break;
  }
}

// One-shot payload read (16 KB, coalesced u64) -> LDS [16][RP] ushort rows.
__device__ __forceinline__ void read_stage(const unsigned* dslot, unsigned short* lds, int tid) {
  const uint64_t* p = (const uint64_t*)dslot;
  uint64_t w[8];
#pragma unroll
  for (int i = 0; i < 8; i++) w[i] = ld64(p + i * 256 + tid);
#pragma unroll
  for (int i = 0; i < 8; i++) {
    int d = i * 256 + tid;  // u64 index: b = d>>7, col = (d&127)*4
    *(uint64_t*)(lds + (d >> 7) * RP + (d & 127) * 4) = w[i];
  }
}
__device__ __forceinline__ void read_stage2(const unsigned* dA, unsigned short* lA,
                                            const unsigned* dB, unsigned short* lB, int tid) {
  const uint64_t* pA = (const uint64_t*)dA;
  const uint64_t* pB = (const uint64_t*)dB;
  uint64_t wa[8], wb[8];
#pragma unroll
  for (int i = 0; i < 8; i++) wa[i] = ld64(pA + i * 256 + tid);
#pragma unroll
  for (int i = 0; i < 8; i++) wb[i] = ld64(pB + i * 256 + tid);
#pragma unroll
  for (int i = 0; i < 8; i++) {
    int d = i * 256 + tid;
    *(uint64_t*)(lA + (d >> 7) * RP + (d & 127) * 4) = wa[i];
    *(uint64_t*)(lB + (d >> 7) * RP + (d & 127) * 4) = wb[i];
  }
}

__global__ __launch_bounds__(256, 1) void gru_fused(
    const float* __restrict__ x, const float* __restrict__ hs,
    const float* __restrict__ Wxz0, const float* __restrict__ Whz0, const float* __restrict__ bhz0,
    const float* __restrict__ Wxr0, const float* __restrict__ Whr0, const float* __restrict__ bhr0,
    const float* __restrict__ Wxz1, const float* __restrict__ Whz1, const float* __restrict__ bhz1,
    const float* __restrict__ Wxr1, const float* __restrict__ Whr1, const float* __restrict__ bhr1,
    const float* __restrict__ Why, const float* __restrict__ by,
    float* __restrict__ out, char* __restrict__ ws, int D) {
  const int tid = threadIdx.x;
  const int wave = tid >> 6;
  const int lane = tid & 63;
  const int lm = lane & 15;
  const int lq = lane >> 4;
  const int rb = tid >> 4;
  const int rj = tid & 15;
  const int m0 = D - 1;

  unsigned* prog = (unsigned*)ws;  // [32], zeroed by memset
  unsigned* h0s = (unsigned*)(ws + 1024);  // [D][32] sentinels
  unsigned* h1s = h0s + D * 32;            // [4][32]
  unsigned* u0s = h1s + 128;               // [2][32]
  unsigned* u1s = u0s + 64;                // [2][32]
  unsigned* h0d = (unsigned*)(ws + 16384); // [D][4096] payload (16KB/slot)
  unsigned* h1d = h0d + (size_t)D * 4096;  // [4][4096]
  unsigned* u0d = h1d + 4 * 4096;          // [2][4096]
  unsigned* u1d = u0d + 2 * 4096;          // [2][4096]

  __shared__ unsigned short stA[16 * RP];
  __shared__ unsigned short stB[16 * RP];
  __shared__ unsigned short stC[16 * RP];
  __shared__ float red[5][4][16][17];  // planes: 0=z 1=xr 2=hr 3=out 4=g

  const bool L0 = (blockIdx.x < 32);
  const int wg = L0 ? blockIdx.x : (blockIdx.x - 32);
  const int j0 = wg << 4;
  const bool OW = (!L0) && (wg < 8);
  const int jrow = j0 + lm;

  // ---- initial hidden state -> payload slot 0, sentinel tag 1 ----
  {
    float h0v = hs[((size_t)rb * 2 + (L0 ? 0 : 1)) * Hv + j0 + rj];
    store_slice(L0 ? h0d : h1d, rb, j0, rj, h0v);
    __syncthreads();  // full drain = vmcnt(0): payload ack'd before sentinel
    if (tid == 0) st32((L0 ? h0s : h1s) + wg, 1u);
  }

  if (L0) {
    v8bf wzx0 = cvt8(Wxz0 + (size_t)jrow * Iv + wave * 32 + lq * 8);
    v8bf wrx0 = cvt8(Wxr0 + (size_t)jrow * Iv + wave * 32 + lq * 8);
    v8bf wzh[4], wrh[4];
#pragma unroll
    for (int kb = 0; kb < 4; kb++) {
      int k = wave * 128 + kb * 32 + lq * 8;
      wzh[kb] = cvt8(Whz0 + (size_t)jrow * Hv + k);
      wrh[kb] = cvt8(Whr0 + (size_t)jrow * Hv + k);
    }
    float bz = bhz0[j0 + rj], br = bhr0[j0 + rj];

    const int xk = wave * 32 + lq * 8;
    float4 xp0 = *(const float4*)(x + ((size_t)lm * Sv + 0) * Iv + xk);
    float4 xp1 = *(const float4*)(x + ((size_t)lm * Sv + 0) * Iv + xk + 4);

    for (int t = 0; t < Sv; ++t) {
      poll1(h0s + (t & m0) * 32, (unsigned)(t + 1), tid);
      read_stage(h0d + (size_t)(t & m0) * 4096, stA, tid);
      v8bf ax;
      {
        float xf[8] = {xp0.x, xp0.y, xp0.z, xp0.w, xp1.x, xp1.y, xp1.z, xp1.w};
#pragma unroll
        for (int i = 0; i < 8; i++) ax[i] = (__bf16)xf[i];
      }
      if (t + 1 < Sv) {  // prefetch early: overlaps both hops, done before B3
        xp0 = *(const float4*)(x + ((size_t)lm * Sv + (t + 1)) * Iv + xk);
        xp1 = *(const float4*)(x + ((size_t)lm * Sv + (t + 1)) * Iv + xk + 4);
      }
      lgkm_barrier();  // B1: stage visible (LDS-only)
      float hval = bf2f(stA[rb * RP + j0 + rj]);
      const unsigned short* hrow = stA + lm * RP;
      v8bf ah[4];
#pragma unroll
      for (int kb = 0; kb < 4; kb++)
        ah[kb] = *(const v8bf*)(hrow + wave * 128 + kb * 32 + lq * 8);
      v4f az = {0, 0, 0, 0}, axr = {0, 0, 0, 0}, ahr = {0, 0, 0, 0};
      az = MFMA(ax, wzx0, az);
      axr = MFMA(ax, wrx0, axr);
#pragma unroll
      for (int kb = 0; kb < 4; kb++) {
        az = MFMA(ah[kb], wzh[kb], az);
        ahr = MFMA(ah[kb], wrh[kb], ahr);
      }
#pragma unroll
      for (int v = 0; v < 4; v++) {
        red[0][wave][lq * 4 + v][lm] = az[v];
        red[1][wave][lq * 4 + v][lm] = axr[v];
        red[2][wave][lq * 4 + v][lm] = ahr[v];
      }
      lgkm_barrier();  // B2 (LDS-only)
      float zs = 0, xrs = 0, hrs = 0;
#pragma unroll
      for (int w = 0; w < 4; w++) {
        zs += red[0][w][rb][rj];
        xrs += red[1][w][rb][rj];
        hrs += red[2][w][rb][rj];
      }
      float z = sigf(zs + bz);
      float r = sigf(xrs + hrs + br);
      store_slice(u0d + (size_t)(t & 1) * 4096, rb, j0, rj, r * hval);
      __syncthreads();  // B3: FULL drain (u stores ack'd) before sentinel
      if (tid == 0) st32(u0s + (t & 1) * 32 + wg, (unsigned)(t + 1));
      poll1(u0s + (t & 1) * 32, (unsigned)(t + 1), tid);
      read_stage(u0d + (size_t)(t & 1) * 4096, stB, tid);
      lgkm_barrier();  // B4 (LDS-only)
      const unsigned short* urow = stB + lm * RP;
      v4f ag = {0, 0, 0, 0};
#pragma unroll
      for (int kb = 0; kb < 4; kb++) {
        v8bf au = *(const v8bf*)(urow + wave * 128 + kb * 32 + lq * 8);
        ag = MFMA(au, wrh[kb], ag);
      }
#pragma unroll
      for (int v = 0; v < 4; v++) red[4][wave][lq * 4 + v][lm] = ag[v];
      lgkm_barrier();  // B5 (LDS-only)
      float gs = 0;
#pragma unroll
      for (int w = 0; w < 4; w++) gs += red[4][w][rb][rj];
      float g = tanh_fast(xrs + gs + br);  // faithful to source bug
      float hn = z * hval + (1.f - z) * g;
      if (t >= D - 1) {  // backpressure vs L1's y0 consumption: gate ALL
        unsigned need = (unsigned)(t - D + 2), it = 0;
        while (ld32(prog + (tid & 31)) < need)
          if (++it > (1u << 20)) break;
      }
      store_slice(h0d + (size_t)((t + 1) & m0) * 4096, rb, j0, rj, hn);
      if (t == Sv - 1) out[(size_t)Bv * Sv * Ov + ((size_t)rb * 2 + 0) * Hv + j0 + rj] = hn;
      __syncthreads();  // B6: FULL drain (h stores ack'd) before sentinel
      if (tid == 0) st32(h0s + ((t + 1) & m0) * 32 + wg, (unsigned)(t + 2));
    }
  } else {
    v8bf wzx1[4], wrx1[4], wzh[4], wrh[4], wo[4];
#pragma unroll
    for (int kb = 0; kb < 4; kb++) {
      int k = wave * 128 + kb * 32 + lq * 8;
      wzx1[kb] = cvt8(Wxz1 + (size_t)jrow * Hv + k);
      wrx1[kb] = cvt8(Wxr1 + (size_t)jrow * Hv + k);
      wzh[kb] = cvt8(Whz1 + (size_t)jrow * Hv + k);
      wrh[kb] = cvt8(Whr1 + (size_t)jrow * Hv + k);
      if (OW) wo[kb] = cvt8(Why + (size_t)jrow * Hv + k);
    }
    float bz = bhz1[j0 + rj], br = bhr1[j0 + rj];
    float bo = OW ? by[j0 + rj] : 0.f;

    for (int t = 0; t < Sv; ++t) {
      // y0_t = h0 production tag t+2 at slot (t+1)&m0; h1_t = tag t+1 at t&3
      poll2(h0s + ((t + 1) & m0) * 32, (unsigned)(t + 2),
            h1s + (t & 3) * 32, (unsigned)(t + 1), tid);
      read_stage2(h0d + (size_t)((t + 1) & m0) * 4096, stA,
                  h1d + (size_t)(t & 3) * 4096, stB, tid);
      lgkm_barrier();  // B1: all waves' loads done (LDS writes are data-dep)
      if (tid == 0) st32(prog + wg, (unsigned)(t + 1));  // y0_t consumed: unblock L0 early
      float hval = bf2f(stB[rb * RP + j0 + rj]);
      const unsigned short* yrow = stA + lm * RP;
      const unsigned short* hrow = stB + lm * RP;
      v4f az = {0, 0, 0, 0}, axr = {0, 0, 0, 0}, ahr = {0, 0, 0, 0}, ao = {0, 0, 0, 0};
      v8bf ahf[4];
#pragma unroll
      for (int kb = 0; kb < 4; kb++) {
        int k = wave * 128 + kb * 32 + lq * 8;
        v8bf ay = *(const v8bf*)(yrow + k);
        ahf[kb] = *(const v8bf*)(hrow + k);
        az = MFMA(ay, wzx1[kb], az);
        az = MFMA(ahf[kb], wzh[kb], az);
        axr = MFMA(ay, wrx1[kb], axr);
        ahr = MFMA(ahf[kb], wrh[kb], ahr);
      }
      if (OW && t > 0) {
#pragma unroll
        for (int kb = 0; kb < 4; kb++) ao = MFMA(ahf[kb], wo[kb], ao);  // out_{t-1}
      }
#pragma unroll
      for (int v = 0; v < 4; v++) {
        red[0][wave][lq * 4 + v][lm] = az[v];
        red[1][wave][lq * 4 + v][lm] = axr[v];
        red[2][wave][lq * 4 + v][lm] = ahr[v];
        if (OW) red[3][wave][lq * 4 + v][lm] = ao[v];
      }
      lgkm_barrier();  // B2 (LDS-only)
      float zs = 0, xrs = 0, hrs = 0, os = 0;
#pragma unroll
      for (int w = 0; w < 4; w++) {
        zs += red[0][w][rb][rj];
        xrs += red[1][w][rb][rj];
        hrs += red[2][w][rb][rj];
        if (OW) os += red[3][w][rb][rj];
      }
      float z = sigf(zs + bz);
      float r = sigf(xrs + hrs + br);
      store_slice(u1d + (size_t)(t & 1) * 4096, rb, j0, rj, r * hval);
      __syncthreads();  // B3: FULL drain before sentinel
      if (tid == 0) st32(u1s + (t & 1) * 32 + wg, (unsigned)(t + 1));
      poll1(u1s + (t & 1) * 32, (unsigned)(t + 1), tid);
      read_stage(u1d + (size_t)(t & 1) * 4096, stC, tid);
      lgkm_barrier();  // B4 (LDS-only)
      const unsigned short* urow = stC + lm * RP;
      v4f ag = {0, 0, 0, 0};
#pragma unroll
      for (int kb = 0; kb < 4; kb++) {
        v8bf au = *(const v8bf*)(urow + wave * 128 + kb * 32 + lq * 8);
        ag = MFMA(au, wrh[kb], ag);
      }
#pragma unroll
      for (int v = 0; v < 4; v++) red[4][wave][lq * 4 + v][lm] = ag[v];
      lgkm_barrier();  // B5 (LDS-only)
      float gs = 0;
#pragma unroll
      for (int w = 0; w < 4; w++) gs += red[4][w][rb][rj];
      float g = tanh_fast(xrs + gs + br);
      float hn = z * hval + (1.f - z) * g;
      store_slice(h1d + (size_t)((t + 1) & 3) * 4096, rb, j0, rj, hn);
      if (t == Sv - 1) out[(size_t)Bv * Sv * Ov + ((size_t)rb * 2 + 1) * Hv + j0 + rj] = hn;
      __syncthreads();  // B6: FULL drain before sentinel
      if (tid == 0) st32(h1s + ((t + 1) & 3) * 32 + wg, (unsigned)(t + 2));
      // HBM out-store issued AFTER the h1 post: its ack drains at next step's
      // B3, ~2 exchange-latencies of overlap. Keeps OW blocks off the
      // critical path of the coupled exchange.
      if (OW && t > 0) out[((size_t)rb * Sv + (t - 1)) * Ov + j0 + rj] = os + bo;
    }
    if (OW) {  // tail: out_{S-1} from y1_{S-1} = h1 tag S+1 at slot S&3
      poll1(h1s + (Sv & 3) * 32, (unsigned)(Sv + 1), tid);
      read_stage(h1d + (size_t)(Sv & 3) * 4096, stB, tid);
      __syncthreads();
      const unsigned short* hrow = stB + lm * RP;
      v4f ao = {0, 0, 0, 0};
#pragma unroll
      for (int kb = 0; kb < 4; kb++) {
        v8bf ah = *(const v8bf*)(hrow + wave * 128 + kb * 32 + lq * 8);
        ao = MFMA(ah, wo[kb], ao);
      }
#pragma unroll
      for (int v = 0; v < 4; v++) red[3][wave][lq * 4 + v][lm] = ao[v];
      __syncthreads();
      float os = 0;
#pragma unroll
      for (int w = 0; w < 4; w++) os += red[3][w][rb][rj];
      out[((size_t)rb * Sv + (Sv - 1)) * Ov + j0 + rj] = os + bo;
    }
  }
}

extern "C" void kernel_launch(void* const* d_in, const int* in_sizes, int n_in,
                              void* d_out, int out_size, void* d_ws, size_t ws_size,
                              hipStream_t stream) {
  const float* x = (const float*)d_in[0];
  const float* hs = (const float*)d_in[1];
  const float* Wxz0 = (const float*)d_in[2];
  const float* Whz0 = (const float*)d_in[3];
  const float* bhz0 = (const float*)d_in[4];
  const float* Wxr0 = (const float*)d_in[5];
  const float* Whr0 = (const float*)d_in[6];
  const float* bhr0 = (const float*)d_in[7];
  const float* Wxz1 = (const float*)d_in[8];
  const float* Whz1 = (const float*)d_in[9];
  const float* bhz1 = (const float*)d_in[10];
  const float* Wxr1 = (const float*)d_in[11];
  const float* Whr1 = (const float*)d_in[12];
  const float* bhr1 = (const float*)d_in[13];
  const float* Why = (const float*)d_in[14];
  const float* by = (const float*)d_in[15];
  float* out = (float*)d_out;

  // y0-ring depth: largest pow2 (<=64, >=4) fitting ws
  int D = 64;
  while (D > 4 && 16384 + (size_t)(D + 8) * 16384 > ws_size) D >>= 1;

  hipMemsetAsync(d_ws, 0, 12288, stream);  // zero prog + all sentinel arrays
  hipLaunchKernelGGL(gru_fused, dim3(64), dim3(256), 0, stream,
                     x, hs, Wxz0, Whz0, bhz0, Wxr0, Whr0, bhr0,
                     Wxz1, Whz1, bhz1, Wxr1, Whr1, bhr1, Why, by,
                     out, (char*)d_ws, D);
}